// Round 10
// baseline (363.741 us; speedup 1.0000x reference)
//
#include <hip/hip_runtime.h>
#include <hip/hip_bf16.h>

// ---------------------------------------------------------------------------
// Conformer block: bf16-MFMA GEMMs (XCD-swizzled, counted-vmcnt pipelined,
// BM=64 high-occupancy variant for small-N) + bf16-MFMA flash attention with
// async-staged K/V, defer-max softmax, setprio. RoPE fused into QKV epilogue
// (table); GLU fused into pw1 (packed weights); bf16 residual stream.
// B=8, T=1024, D=512, HID=1024, C=1024, K=31, H=8, dh=64.  M = B*T = 8192.
// ---------------------------------------------------------------------------

#define M_ROWS 8192

using bf16x8 = __attribute__((ext_vector_type(8))) short;
using f32x4  = __attribute__((ext_vector_type(4))) float;
using s8v    = __attribute__((ext_vector_type(8))) short;
using s4v    = __attribute__((ext_vector_type(4))) short;

__device__ __forceinline__ float sigmoid_(float v) { return 1.f / (1.f + expf(-v)); }

__device__ __forceinline__ float bf2f(short s) {
  return __uint_as_float(((unsigned)(unsigned short)s) << 16);
}
__device__ __forceinline__ short f2bf(float f) {
  unsigned u = __float_as_uint(f);
  unsigned r = (u + 0x7fffu + ((u >> 16) & 1u)) >> 16;
  return (short)r;
}

__device__ __forceinline__ void gl16(const void* g, void* l) {
  __builtin_amdgcn_global_load_lds((const __attribute__((address_space(1))) void*)g,
                                   (__attribute__((address_space(3))) void*)l, 16, 0, 0);
}

// ---------------------------------------------------------------------------
// bf16 MFMA GEMM: outb[M,N] = epi(A[M,K] @ Bt[N,K]^T + bias). BK=32.
// BM=128: 2x2 wave grid (wave tile 64 x BN/2). BM=64: 1x4 (wave tile 64 x BN/4).
// K-loop: 2-buffer LDS, counted vmcnt (never 0 in steady state), raw barriers.
// EPI: 1 swish->bf16 | 2 resb+acc+bias->bf16 | 3 resb+0.5*(acc+bias)->bf16
//      4 QKV (BM=128): table-RoPE q/k ->bf16 (B,H,T,64); v->bf16 (B,H,64,T)
//      6 pw1+GLU (BM=128, packed weights): a*sigmoid(gate)->bf16
// ---------------------------------------------------------------------------
template <int BM, int BN, int EPI>
__global__ __launch_bounds__(256) void mgemm(
    const short* __restrict__ A, const short* __restrict__ Bt,
    const float* __restrict__ bias, const float* __restrict__ res,
    const short* __restrict__ resb, short* __restrict__ outb, int M, int N, int K) {
  constexpr int WR = BM / 64;        // wave-grid rows
  constexpr int WC = 4 / WR;         // wave-grid cols
  constexpr int NF = BN / (16 * WC); // N-frags per wave
  __shared__ __align__(16) short As[2][BM * 32];
  __shared__ __align__(16) short Bs[2][BN * 32];
  __shared__ __align__(16) short vstg[EPI == 4 ? 64 * 132 : 1];  // v^T staging
  const int tid = threadIdx.x;
  const int lane = tid & 63, wid = tid >> 6;
  const int wr = wid / WC, wc = wid % WC;
  // ---- XCD-aware swizzle: contiguous bm-chunk per XCD for A-panel L2 reuse.
  const int nbx = gridDim.x;
  const int nwg = nbx * gridDim.y;
  int id = blockIdx.y * nbx + blockIdx.x;
  id = (id & 7) * (nwg >> 3) + (id >> 3);
  const int bm = (id / nbx) * BM;
  const int bn = (id % nbx) * BN;
  f32x4 acc[4][NF];
#pragma unroll
  for (int m = 0; m < 4; ++m)
#pragma unroll
    for (int n = 0; n < NF; ++n) acc[m][n] = (f32x4){0.f, 0.f, 0.f, 0.f};
  const short* Ablk = A + (size_t)bm * K;
  const short* Bblk = Bt + (size_t)bn * K;
  const int r0 = tid >> 2, ks = (tid & 3) << 3;  // staging row / k-offset
#define STAGE(buf, k0)                                                              \
  do {                                                                              \
    gl16(Ablk + (size_t)r0 * K + (k0) + ks, (char*)As[buf] + wid * 1024);           \
    if (BM == 128)                                                                  \
      gl16(Ablk + (size_t)(r0 + 64) * K + (k0) + ks, (char*)As[buf] + 4096 + wid * 1024); \
    gl16(Bblk + (size_t)r0 * K + (k0) + ks, (char*)Bs[buf] + wid * 1024);           \
    if (BN == 128)                                                                  \
      gl16(Bblk + (size_t)(r0 + 64) * K + (k0) + ks, (char*)Bs[buf] + 4096 + wid * 1024); \
  } while (0)

  STAGE(0, 0);
  STAGE(1, 32);
  const int NS = K >> 5;
  const int arow = wr * 64 + (lane & 15);
  const int brow = wc * (BN / WC) + (lane & 15);
  const int koff = (lane >> 4) << 3;
  for (int i = 0; i < NS; ++i) {
    // wait: this iter's buffer landed; next iter's stage may remain in flight.
    if (i + 1 < NS) {
      if constexpr (BM + BN == 256) asm volatile("s_waitcnt vmcnt(4)" ::: "memory");
      else if constexpr (BM + BN == 192) asm volatile("s_waitcnt vmcnt(3)" ::: "memory");
      else asm volatile("s_waitcnt vmcnt(2)" ::: "memory");
    } else {
      asm volatile("s_waitcnt vmcnt(0)" ::: "memory");
    }
    __builtin_amdgcn_s_barrier();
    asm volatile("" ::: "memory");  // fence: no LDS read hoists above barrier
    const int cur = i & 1;
    bf16x8 af[4], bfr[NF];
#pragma unroll
    for (int m = 0; m < 4; ++m)
      af[m] = *reinterpret_cast<const bf16x8*>(&As[cur][(arow + m * 16) * 32 + koff]);
#pragma unroll
    for (int n = 0; n < NF; ++n)
      bfr[n] = *reinterpret_cast<const bf16x8*>(&Bs[cur][(brow + n * 16) * 32 + koff]);
    asm volatile("s_waitcnt lgkmcnt(0)" ::: "memory");  // my reads in regs
    __builtin_amdgcn_s_barrier();                       // all waves' reads done
    if (((i + 2) << 5) < K) STAGE(cur, (i + 2) << 5);   // safe to overwrite
#pragma unroll
    for (int m = 0; m < 4; ++m)
#pragma unroll
      for (int n = 0; n < NF; ++n)
        acc[m][n] = __builtin_amdgcn_mfma_f32_16x16x32_bf16(af[m], bfr[n], acc[m][n], 0, 0, 0);
  }
#undef STAGE
  const int orow0 = bm + wr * 64 + ((lane >> 4) << 2);
  const int ocol0 = bn + wc * (BN / WC) + (lane & 15);

  if constexpr (EPI == 4) {
    // ---- QKV epilogue. sel: 0=q (pos=h, *scale), 1=k (pos=t), 2=v^T.
    const int sel = bn >> 9;
    const float2* tbl = (const float2*)res;  // [1024][32] (cos,sin)
    if (sel == 2) {
      const int b_ = bm >> 10, t0v = bm & 1023;
      const int hb = (bn & 511) >> 6;
#pragma unroll
      for (int pass = 0; pass < 2; ++pass) {
        __syncthreads();
        if (wc == pass) {
#pragma unroll
          for (int m = 0; m < 4; ++m) {
            const int rl = wr * 64 + ((lane >> 4) << 2) + m * 16;  // t_local
#pragma unroll
            for (int n = 0; n < NF; ++n) {
              const int dl = (lane & 15) + n * 16;
              const float bv = bias[bn + wc * 64 + dl];
#pragma unroll
              for (int r = 0; r < 4; ++r)
                vstg[dl * 132 + rl + r] = f2bf(acc[m][n][r] + bv);
            }
          }
        }
        __syncthreads();
#pragma unroll
        for (int it = 0; it < 4; ++it) {
          const int c = tid + (it << 8);  // 0..1023
          const int d = c >> 4, t8 = (c & 15) << 3;
          const s8v val = *reinterpret_cast<const s8v*>(&vstg[d * 132 + t8]);
          *reinterpret_cast<s8v*>(
              &outb[(size_t)8388608 + (((size_t)((b_ << 3) + hb + pass)) << 16) +
                    ((size_t)d << 10) + t0v + t8]) = val;
        }
      }
    } else {
      const float qsc = (sel == 0) ? 0.04419417382415922f : 1.f;  // 1/sqrt(512)
#pragma unroll
      for (int n = 0; n < NF; ++n) {
        const int col = ocol0 + n * 16;
        const int h = (col >> 6) & 7, d = col & 63;
        const int p = d >> 1;
        const float bv = bias[col];
#pragma unroll
        for (int m = 0; m < 4; ++m) {
#pragma unroll
          for (int r = 0; r < 4; ++r) {
            const int row = orow0 + m * 16 + r;
            const int b_ = row >> 10, t_ = row & 1023;
            const int pos = (sel == 0) ? h : t_;
            const float2 cs = tbl[pos * 32 + p];
            float vv = acc[m][n][r] + bv;
            const float pv = __shfl_xor(vv, 1);
            float o = ((lane & 1) == 0) ? (vv * cs.x - pv * cs.y) : (vv * cs.x + pv * cs.y);
            outb[(size_t)sel * 4194304 + (((size_t)((b_ << 3) + h)) << 16) + ((size_t)t_ << 6) + d] =
                f2bf(o * qsc);
          }
        }
      }
    }
  } else if constexpr (EPI == 6) {
    // ---- pw1 + GLU: packed weights put (a, gate) in frags (2np, 2np+1).
    const int j = bn >> 7;
#pragma unroll
    for (int m = 0; m < 4; ++m) {
#pragma unroll
      for (int np = 0; np < NF / 2; ++np) {
        const int gc = (j << 6) + ((wc * 2 + np) << 4) + (lane & 15);
        const float ba = bias[gc];
        const float bg = bias[1024 + gc];
#pragma unroll
        for (int r = 0; r < 4; ++r) {
          const int row = orow0 + m * 16 + r;
          const float a = acc[m][2 * np][r] + ba;
          const float g = acc[m][2 * np + 1][r] + bg;
          outb[(size_t)row * 1024 + gc] = f2bf(a * sigmoid_(g));
        }
      }
    }
  } else {
#pragma unroll
    for (int m = 0; m < 4; ++m) {
#pragma unroll
      for (int n = 0; n < NF; ++n) {
        const int col = ocol0 + n * 16;
        const float bv = bias[col];
#pragma unroll
        for (int r = 0; r < 4; ++r) {
          const int row = orow0 + m * 16 + r;
          float v = acc[m][n][r] + bv;
          if constexpr (EPI == 1) {
            v = v * sigmoid_(v);
          } else if constexpr (EPI == 2) {
            v += bf2f(resb[(size_t)row * N + col]);
          } else if constexpr (EPI == 3) {
            v = bf2f(resb[(size_t)row * N + col]) + 0.5f * v;
          }
          outb[(size_t)row * N + col] = f2bf(v);
        }
      }
    }
  }
}

// ---------------------------------------------------------------------------
// RoPE table: tbl[t][p] = (cos, sin) of t * 10000^(-p/32). 1024x32 float2.
// ---------------------------------------------------------------------------
__global__ __launch_bounds__(256) void rope_tbl_kernel(float* __restrict__ tbl) {
  const int i = blockIdx.x * 256 + threadIdx.x;  // 32768
  const int t = i >> 5, p = i & 31;
  const float inv = exp2f(-(float)p * 0.41524101186092f);  // 10000^(-p/32)
  float s, c;
  sincosf((float)t * inv, &s, &c);
  tbl[i * 2] = c;
  tbl[i * 2 + 1] = s;
}

// ---------------------------------------------------------------------------
// LayerNorm over last dim (512), bf16 input. One block (256 threads) per row.
// ---------------------------------------------------------------------------
template <typename OT>
__global__ __launch_bounds__(256) void ln_kernel(
    const short* __restrict__ in, const float* __restrict__ g,
    const float* __restrict__ b, OT* __restrict__ out) {
  __shared__ float sm[4];
  const size_t row = blockIdx.x;
  const int tid = threadIdx.x;
  const short* x = in + (row << 9);
  const int pr = *reinterpret_cast<const int*>(&x[tid << 1]);
  const float v0 = bf2f((short)(pr & 0xffff));
  const float v1 = bf2f((short)(((unsigned)pr) >> 16));
  float s = v0 + v1;
  for (int o = 32; o; o >>= 1) s += __shfl_xor(s, o);
  if ((tid & 63) == 0) sm[tid >> 6] = s;
  __syncthreads();
  const float mean = (sm[0] + sm[1] + sm[2] + sm[3]) * (1.f / 512.f);
  __syncthreads();
  const float d0 = v0 - mean, d1 = v1 - mean;
  float q = d0 * d0 + d1 * d1;
  for (int o = 32; o; o >>= 1) q += __shfl_xor(q, o);
  if ((tid & 63) == 0) sm[tid >> 6] = q;
  __syncthreads();
  const float var = (sm[0] + sm[1] + sm[2] + sm[3]) * (1.f / 512.f);
  const float inv = rsqrtf(var + 1e-5f);
  const float2 gv = *reinterpret_cast<const float2*>(&g[tid << 1]);
  const float2 bv = *reinterpret_cast<const float2*>(&b[tid << 1]);
  const float o0 = d0 * inv * gv.x + bv.x;
  const float o1 = d1 * inv * gv.y + bv.y;
  if constexpr (sizeof(OT) == 2) {
    const int pk = (int)(unsigned short)f2bf(o0) | ((int)(unsigned short)f2bf(o1) << 16);
    *reinterpret_cast<int*>(&out[(row << 9) + (tid << 1)]) = pk;
  } else {
    float2 o = {o0, o1};
    *reinterpret_cast<float2*>(&out[(row << 9) + (tid << 1)]) = o;
  }
}

// ---------------------------------------------------------------------------
// MFMA flash attention. One block (4 waves) per (b,h,64-q-tile), XCD-swizzled.
// q,k bf16 (B,H,T,64) pre-roped (q pre-scaled); v bf16 TRANSPOSED (B,H,64,T).
// Async-staged K/V (T14), defer-max softmax (T13, THR=8), setprio (T5).
// ---------------------------------------------------------------------------
__global__ __launch_bounds__(256) void attn_mfma_kernel(
    const short* __restrict__ q, const short* __restrict__ k,
    const short* __restrict__ vt, short* __restrict__ ctx) {
  __shared__ __align__(16) short Qs[64][72];   // [q][d]
  __shared__ __align__(16) short Ks[64][72];   // [k][d]
  __shared__ __align__(16) short VsT[64][72];  // [d][k]
  __shared__ __align__(16) short Ps[64][72];   // [q][k]
  const int bx = ((blockIdx.x & 7) << 7) | (blockIdx.x >> 3);  // nwg=1024, cpx=128
  const int bh = bx >> 4, qt = bx & 15;
  const int b_ = bh >> 3, h_ = bh & 7;
  const int tid = threadIdx.x, lane = tid & 63, w = tid >> 6;
  const int t0 = qt << 6;
  const short* qbase = q + ((size_t)bh << 16) + ((size_t)t0 << 6);
  const short* kbase = k + ((size_t)bh << 16);
  const short* vtbase = vt + ((size_t)bh << 16);
  const int sr = tid >> 2, scg = (tid & 3) << 4;
  // ---- stage Q and tile 0 of K/V
  {
    const s8v a = *reinterpret_cast<const s8v*>(&qbase[(size_t)sr * 64 + scg]);
    const s8v b = *reinterpret_cast<const s8v*>(&qbase[(size_t)sr * 64 + scg + 8]);
    *reinterpret_cast<s8v*>(&Qs[sr][scg]) = a;
    *reinterpret_cast<s8v*>(&Qs[sr][scg + 8]) = b;
    const s8v k0a = *reinterpret_cast<const s8v*>(&kbase[(size_t)sr * 64 + scg]);
    const s8v k0b = *reinterpret_cast<const s8v*>(&kbase[(size_t)sr * 64 + scg + 8]);
    *reinterpret_cast<s8v*>(&Ks[sr][scg]) = k0a;
    *reinterpret_cast<s8v*>(&Ks[sr][scg + 8]) = k0b;
    const s8v v0a = *reinterpret_cast<const s8v*>(&vtbase[((size_t)sr << 10) + scg]);
    const s8v v0b = *reinterpret_cast<const s8v*>(&vtbase[((size_t)sr << 10) + scg + 8]);
    *reinterpret_cast<s8v*>(&VsT[sr][scg]) = v0a;
    *reinterpret_cast<s8v*>(&VsT[sr][scg + 8]) = v0b;
  }
  __syncthreads();
  const int fr = lane & 15, fg = lane >> 4;
  const int koff0 = fg << 3;
  bf16x8 qf[2];
  qf[0] = *reinterpret_cast<const bf16x8*>(&Qs[w * 16 + fr][koff0]);
  qf[1] = *reinterpret_cast<const bf16x8*>(&Qs[w * 16 + fr][32 + koff0]);
  float m[4] = {-1e30f, -1e30f, -1e30f, -1e30f};
  float l[4] = {0.f, 0.f, 0.f, 0.f};
  f32x4 outv[4];
#pragma unroll
  for (int n = 0; n < 4; ++n) outv[n] = (f32x4){0.f, 0.f, 0.f, 0.f};

  for (int i = 0; i < 16; ++i) {
    // ---- T14: issue next tile's global loads; consumed after the PV barrier.
    s8v nk0, nk1, nv0, nv1;
    const bool pf = (i < 15);
    if (pf) {
      const int kn = (i + 1) << 6;
      nk0 = *reinterpret_cast<const s8v*>(&kbase[(size_t)(kn + sr) * 64 + scg]);
      nk1 = *reinterpret_cast<const s8v*>(&kbase[(size_t)(kn + sr) * 64 + scg + 8]);
      nv0 = *reinterpret_cast<const s8v*>(&vtbase[((size_t)sr << 10) + kn + scg]);
      nv1 = *reinterpret_cast<const s8v*>(&vtbase[((size_t)sr << 10) + kn + scg + 8]);
    }
    // ---- S = Q @ K^T
    f32x4 sacc[4];
    __builtin_amdgcn_s_setprio(1);
#pragma unroll
    for (int n = 0; n < 4; ++n) {
      sacc[n] = (f32x4){0.f, 0.f, 0.f, 0.f};
      const bf16x8 kf0 = *reinterpret_cast<const bf16x8*>(&Ks[n * 16 + fr][koff0]);
      const bf16x8 kf1 = *reinterpret_cast<const bf16x8*>(&Ks[n * 16 + fr][32 + koff0]);
      sacc[n] = __builtin_amdgcn_mfma_f32_16x16x32_bf16(qf[0], kf0, sacc[n], 0, 0, 0);
      sacc[n] = __builtin_amdgcn_mfma_f32_16x16x32_bf16(qf[1], kf1, sacc[n], 0, 0, 0);
    }
    __builtin_amdgcn_s_setprio(0);
    // ---- online softmax with defer-max (THR=8)
    float vm[4];
#pragma unroll
    for (int r = 0; r < 4; ++r)
      vm[r] = fmaxf(fmaxf(sacc[0][r], sacc[1][r]), fmaxf(sacc[2][r], sacc[3][r]));
    const bool ok = vm[0] <= m[0] + 8.f && vm[1] <= m[1] + 8.f &&
                    vm[2] <= m[2] + 8.f && vm[3] <= m[3] + 8.f;
    if (__all(ok)) {
      // fast path: keep old max, no rescale (P bounded by e^8)
#pragma unroll
      for (int r = 0; r < 4; ++r) {
        const float p0 = __expf(sacc[0][r] - m[r]), p1 = __expf(sacc[1][r] - m[r]);
        const float p2 = __expf(sacc[2][r] - m[r]), p3 = __expf(sacc[3][r] - m[r]);
        l[r] += p0 + p1 + p2 + p3;
        const int qr = w * 16 + (fg << 2) + r;
        Ps[qr][fr] = f2bf(p0);
        Ps[qr][16 + fr] = f2bf(p1);
        Ps[qr][32 + fr] = f2bf(p2);
        Ps[qr][48 + fr] = f2bf(p3);
      }
    } else {
#pragma unroll
      for (int r = 0; r < 4; ++r) {
        float rm = vm[r];
        rm = fmaxf(rm, __shfl_xor(rm, 1));
        rm = fmaxf(rm, __shfl_xor(rm, 2));
        rm = fmaxf(rm, __shfl_xor(rm, 4));
        rm = fmaxf(rm, __shfl_xor(rm, 8));
        const float nm = fmaxf(m[r], rm);
        const float al = __expf(m[r] - nm);
        m[r] = nm;
        const float p0 = __expf(sacc[0][r] - nm), p1 = __expf(sacc[1][r] - nm);
        const float p2 = __expf(sacc[2][r] - nm), p3 = __expf(sacc[3][r] - nm);
        l[r] = l[r] * al + (p0 + p1 + p2 + p3);
        outv[0][r] *= al; outv[1][r] *= al; outv[2][r] *= al; outv[3][r] *= al;
        const int qr = w * 16 + (fg << 2) + r;
        Ps[qr][fr] = f2bf(p0);
        Ps[qr][16 + fr] = f2bf(p1);
        Ps[qr][32 + fr] = f2bf(p2);
        Ps[qr][48 + fr] = f2bf(p3);
      }
    }
    __syncthreads();  // Ps visible; all QK reads of Ks done
    // ---- out += P @ V
    const bf16x8 pa0 = *reinterpret_cast<const bf16x8*>(&Ps[w * 16 + fr][koff0]);
    const bf16x8 pa1 = *reinterpret_cast<const bf16x8*>(&Ps[w * 16 + fr][32 + koff0]);
    __builtin_amdgcn_s_setprio(1);
#pragma unroll
    for (int n = 0; n < 4; ++n) {
      const bf16x8 vf0 = *reinterpret_cast<const bf16x8*>(&VsT[n * 16 + fr][koff0]);
      const bf16x8 vf1 = *reinterpret_cast<const bf16x8*>(&VsT[n * 16 + fr][32 + koff0]);
      outv[n] = __builtin_amdgcn_mfma_f32_16x16x32_bf16(pa0, vf0, outv[n], 0, 0, 0);
      outv[n] = __builtin_amdgcn_mfma_f32_16x16x32_bf16(pa1, vf1, outv[n], 0, 0, 0);
    }
    __builtin_amdgcn_s_setprio(0);
    __syncthreads();  // all PV reads of VsT/Ps done
    if (pf) {
      *reinterpret_cast<s8v*>(&Ks[sr][scg]) = nk0;
      *reinterpret_cast<s8v*>(&Ks[sr][scg + 8]) = nk1;
      *reinterpret_cast<s8v*>(&VsT[sr][scg]) = nv0;
      *reinterpret_cast<s8v*>(&VsT[sr][scg + 8]) = nv1;
      __syncthreads();
    }
  }
#pragma unroll
  for (int r = 0; r < 4; ++r) {
    float L = l[r];
    L += __shfl_xor(L, 1);
    L += __shfl_xor(L, 2);
    L += __shfl_xor(L, 4);
    L += __shfl_xor(L, 8);
    const float inv = 1.f / L;
    const int t = t0 + w * 16 + (fg << 2) + r;
    const size_t base = (((size_t)((b_ << 10) | t)) << 9) + (h_ << 6);
#pragma unroll
    for (int n = 0; n < 4; ++n)
      ctx[base + n * 16 + fr] = f2bf(outv[n][r] * inv);
  }
}

// ---------------------------------------------------------------------------
// f32 -> bf16 cast (8 elems/thread).
// ---------------------------------------------------------------------------
__global__ __launch_bounds__(256) void cast_bf16_kernel(const float* __restrict__ in,
                                                        short* __restrict__ out) {
  const size_t i = (size_t)blockIdx.x * 256 + threadIdx.x;
  const float4 a = *reinterpret_cast<const float4*>(&in[i * 8]);
  const float4 b = *reinterpret_cast<const float4*>(&in[i * 8 + 4]);
  s8v o = { f2bf(a.x), f2bf(a.y), f2bf(a.z), f2bf(a.w),
            f2bf(b.x), f2bf(b.y), f2bf(b.z), f2bf(b.w) };
  *reinterpret_cast<s8v*>(&out[i * 8]) = o;
}

// ---------------------------------------------------------------------------
// pw1 weight pack: [2048][512] f32 -> interleaved [2048][512] bf16.
// ---------------------------------------------------------------------------
__global__ __launch_bounds__(256) void pack_pw1_kernel(const float* __restrict__ w,
                                                       short* __restrict__ out) {
  const int idx = blockIdx.x * 256 + threadIdx.x;  // 2048*64
  const int pc = idx >> 6, kk = (idx & 63) << 3;
  const int j = pc >> 7, s = (pc >> 4) & 7, fr = pc & 15;
  const int oc = ((s & 1) << 10) + (j << 6) + ((s >> 1) << 4) + fr;
  const float4 a = *reinterpret_cast<const float4*>(&w[(size_t)oc * 512 + kk]);
  const float4 b = *reinterpret_cast<const float4*>(&w[(size_t)oc * 512 + kk + 4]);
  s8v o = { f2bf(a.x), f2bf(a.y), f2bf(a.z), f2bf(a.w),
            f2bf(b.x), f2bf(b.y), f2bf(b.z), f2bf(b.w) };
  *reinterpret_cast<s8v*>(&out[(size_t)pc * 512 + kk]) = o;
}

// ---------------------------------------------------------------------------
// Transpose-cast: in [K,N] f32 -> out [N,K] bf16. Grid (N/32, K/32).
// ---------------------------------------------------------------------------
__global__ __launch_bounds__(256) void tcast_kernel(const float* __restrict__ in,
                                                    short* __restrict__ out, int K, int N) {
  __shared__ float t[32][33];
  const int n0 = blockIdx.x << 5, k0 = blockIdx.y << 5;
  const int tx = threadIdx.x & 31, ty = threadIdx.x >> 5;
  for (int r = ty; r < 32; r += 8) t[r][tx] = in[(size_t)(k0 + r) * N + n0 + tx];
  __syncthreads();
  for (int r = ty; r < 32; r += 8) out[(size_t)(n0 + r) * K + k0 + tx] = f2bf(t[tx][r]);
}

__global__ __launch_bounds__(256) void concat3_kernel(const float* a, const float* b,
                                                      const float* c, float* o) {
  const int i = blockIdx.x * 256 + threadIdx.x;  // 1536
  o[i] = i < 512 ? a[i] : (i < 1024 ? b[i - 512] : c[i - 1024]);
}

// ---------------------------------------------------------------------------
// Depthwise conv K=31 SAME. in bf16 (8,1024,1024), out bf16. 8 ch/thread.
// ---------------------------------------------------------------------------
__global__ __launch_bounds__(256) void dwconv_kernel(
    const short* __restrict__ in, const float* __restrict__ w,
    const float* __restrict__ bias, short* __restrict__ out) {
  const size_t i = (size_t)blockIdx.x * 256 + threadIdx.x;  // 1M
  const int c8 = (int)(i & 127) << 3;
  const size_t bt = i >> 7;
  const int t = (int)(bt & 1023);
  const size_t b = bt >> 10;
  float acc[8];
#pragma unroll
  for (int j = 0; j < 8; ++j) acc[j] = bias[c8 + j];
#pragma unroll
  for (int kk = 0; kk < 31; ++kk) {
    const int tt = t + kk - 15;
    if (tt >= 0 && tt < 1024) {
      const s8v xv = *reinterpret_cast<const s8v*>(&in[(b << 20) + ((size_t)tt << 10) + c8]);
      const float4 w0 = *reinterpret_cast<const float4*>(&w[kk * 1024 + c8]);
      const float4 w1 = *reinterpret_cast<const float4*>(&w[kk * 1024 + c8 + 4]);
      acc[0] = fmaf(bf2f(xv[0]), w0.x, acc[0]);
      acc[1] = fmaf(bf2f(xv[1]), w0.y, acc[1]);
      acc[2] = fmaf(bf2f(xv[2]), w0.z, acc[2]);
      acc[3] = fmaf(bf2f(xv[3]), w0.w, acc[3]);
      acc[4] = fmaf(bf2f(xv[4]), w1.x, acc[4]);
      acc[5] = fmaf(bf2f(xv[5]), w1.y, acc[5]);
      acc[6] = fmaf(bf2f(xv[6]), w1.z, acc[6]);
      acc[7] = fmaf(bf2f(xv[7]), w1.w, acc[7]);
    }
  }
  s8v o;
#pragma unroll
  for (int j = 0; j < 8; ++j) o[j] = f2bf(acc[j]);
  *reinterpret_cast<s8v*>(&out[i << 3]) = o;
}

// ---------------------------------------------------------------------------
// BatchNorm over (B,T) on bf16 y: two-stage deterministic reduction; apply+swish.
// ---------------------------------------------------------------------------
__global__ __launch_bounds__(256) void bn_stats_kernel(
    const short* __restrict__ y, float* __restrict__ ps, float* __restrict__ pq) {
  const int tid = threadIdx.x;
  const int c4 = tid << 2;
  const size_t r0 = (size_t)blockIdx.x * 32;
  float s[4] = {0, 0, 0, 0}, q[4] = {0, 0, 0, 0};
  for (int r = 0; r < 32; ++r) {
    const s4v v = *reinterpret_cast<const s4v*>(&y[((r0 + r) << 10) + c4]);
#pragma unroll
    for (int j = 0; j < 4; ++j) {
      const float f = bf2f(v[j]);
      s[j] += f;
      q[j] = fmaf(f, f, q[j]);
    }
  }
#pragma unroll
  for (int j = 0; j < 4; ++j) {
    ps[(size_t)blockIdx.x * 1024 + c4 + j] = s[j];
    pq[(size_t)blockIdx.x * 1024 + c4 + j] = q[j];
  }
}

__global__ __launch_bounds__(256) void bn_finalize_kernel(
    const float* __restrict__ ps, const float* __restrict__ pq, float* __restrict__ stats) {
  const int c = blockIdx.x * 256 + threadIdx.x;  // 0..1023
  float s = 0.f, q = 0.f;
  for (int i = 0; i < 256; ++i) {
    s += ps[i * 1024 + c];
    q += pq[i * 1024 + c];
  }
  const float mean = s * (1.f / 8192.f);
  const float var = q * (1.f / 8192.f) - mean * mean;
  stats[c] = mean;
  stats[1024 + c] = rsqrtf(fmaxf(var, 0.f) + 1e-5f);
}

__global__ __launch_bounds__(256) void bn_apply_kernel(
    const short* __restrict__ y, const float* __restrict__ g, const float* __restrict__ b,
    const float* __restrict__ stats, short* __restrict__ out) {
  const size_t i = (size_t)blockIdx.x * 256 + threadIdx.x;  // 2M, 4 elems each
  const size_t f = i << 2;
  const int c = (int)(f & 1023);
  const s4v yv = *reinterpret_cast<const s4v*>(&y[f]);
  s4v o;
#pragma unroll
  for (int j = 0; j < 4; ++j) {
    const float v = (bf2f(yv[j]) - stats[c + j]) * stats[1024 + c + j] * g[c + j] + b[c + j];
    o[j] = f2bf(v * sigmoid_(v));
  }
  *reinterpret_cast<s4v*>(&out[f]) = o;
}

// ---------------------------------------------------------------------------
extern "C" void kernel_launch(void* const* d_in, const int* in_sizes, int n_in,
                              void* d_out, int out_size, void* d_ws, size_t ws_size,
                              hipStream_t stream) {
  const float* x        = (const float*)d_in[0];
  const float* ffn1_w1  = (const float*)d_in[1];
  const float* ffn1_b1  = (const float*)d_in[2];
  const float* ffn1_w2  = (const float*)d_in[3];
  const float* ffn1_b2  = (const float*)d_in[4];
  const float* ln_att_g = (const float*)d_in[5];
  const float* ln_att_b = (const float*)d_in[6];
  const float* wq       = (const float*)d_in[7];
  const float* bq       = (const float*)d_in[8];
  const float* wk       = (const float*)d_in[9];
  const float* bk       = (const float*)d_in[10];
  const float* wv       = (const float*)d_in[11];
  const float* bv       = (const float*)d_in[12];
  const float* wo_      = (const float*)d_in[13];
  const float* bo       = (const float*)d_in[14];
  const float* cln_g    = (const float*)d_in[15];
  const float* cln_b    = (const float*)d_in[16];
  const float* pw1_w    = (const float*)d_in[17];
  const float* pw1_b    = (const float*)d_in[18];
  const float* dw_w     = (const float*)d_in[19];
  const float* dw_b     = (const float*)d_in[20];
  const float* bn_g     = (const float*)d_in[21];
  const float* bn_b     = (const float*)d_in[22];
  const float* pw2_w    = (const float*)d_in[23];
  const float* pw2_b    = (const float*)d_in[24];
  const float* ffn2_w1  = (const float*)d_in[25];
  const float* ffn2_b1  = (const float*)d_in[26];
  const float* ffn2_w2  = (const float*)d_in[27];
  const float* ffn2_b2  = (const float*)d_in[28];
  const float* ln_out_g = (const float*)d_in[29];
  const float* ln_out_b = (const float*)d_in[30];

  char* wsb = (char*)d_ws;
  const size_t MB = 1u << 20;
  // Region A: residual stream bf16 (8 MB)
  short* buf_y = (short*)(wsb);
  // Region B (64 MB, phase-overlaid)
  char* Bre = wsb + 16 * MB;
  short* qkv16 = (short*)(Bre);            // MHSA: q,k (B,H,T,64) + v^T (B,H,64,T), 24 MB
  short* lnq  = (short*)(Bre + 48 * MB);   //        LN out bf16 (8 MB)
  short* ctx  = (short*)(Bre + 56 * MB);   //        ctx bf16 (8 MB)
  short* h1   = (short*)(Bre);             // FFN: hidden bf16 (16 MB)
  short* xb   = (short*)(Bre + 16 * MB);   // x bf16 (8 MB): FFN1 A-input + residual
  short* gluo = (short*)(Bre);             // conv: fused pw1+GLU out bf16 (16 MB)
  short* bno  = (short*)(Bre + 48 * MB);   //       bn out bf16 (16 MB)
  // Region C (32 MB, phase-overlaid)
  char* Cre = wsb + 80 * MB;
  short* lnc  = (short*)(Cre);             // conv LN out bf16 (8 MB)
  short* dwo16= (short*)(Cre + 8 * MB);    // dwconv out bf16 (16 MB)
  // Region D: weights / stats / rope table (~13 MB)
  char* Dre = wsb + 112 * MB;
  short* w_f1w1 = (short*)(Dre);            // [1024,512]
  short* w_f1w2 = (short*)(Dre + 1 * MB);   // [512,1024]
  short* w_qkv  = (short*)(Dre + 2 * MB);   // [1536,512]
  short* w_wo   = (short*)(Dre + 3 * MB + 512 * 1024);  // [512,512]
  short* w_pw1  = (short*)(Dre + 4 * MB);   // [2048,512] packed-interleaved
  short* w_pw2  = (short*)(Dre + 6 * MB);   // [512,1024]
  short* w_f2w1 = (short*)(Dre + 7 * MB);   // [1024,512]
  short* w_f2w2 = (short*)(Dre + 8 * MB);   // [512,1024]
  float* bqkv   = (float*)(Dre + 9 * MB);   // [1536]
  float* ps     = (float*)(Dre + 9 * MB + 8192);
  float* pq     = (float*)(Dre + 10 * MB + 8192);
  float* stats  = (float*)(Dre + 11 * MB + 8192);
  float* rtbl   = (float*)(Dre + 12 * MB);  // [1024][32] float2 = 256 KB

  const dim3 blk(256);

  // ---- input/weight prep (bf16 casts / transposes / packs), graph-safe
  cast_bf16_kernel<<<2048, blk, 0, stream>>>(x, xb);
  tcast_kernel<<<dim3(32, 16), blk, 0, stream>>>(ffn1_w1, w_f1w1, 512, 1024);
  tcast_kernel<<<dim3(16, 32), blk, 0, stream>>>(ffn1_w2, w_f1w2, 1024, 512);
  tcast_kernel<<<dim3(16, 16), blk, 0, stream>>>(wq, w_qkv, 512, 512);
  tcast_kernel<<<dim3(16, 16), blk, 0, stream>>>(wk, w_qkv + 512 * 512, 512, 512);
  tcast_kernel<<<dim3(16, 16), blk, 0, stream>>>(wv, w_qkv + 1024 * 512, 512, 512);
  tcast_kernel<<<dim3(16, 16), blk, 0, stream>>>(wo_, w_wo, 512, 512);
  pack_pw1_kernel<<<512, blk, 0, stream>>>(pw1_w, w_pw1);
  cast_bf16_kernel<<<256, blk, 0, stream>>>(pw2_w, w_pw2);
  tcast_kernel<<<dim3(32, 16), blk, 0, stream>>>(ffn2_w1, w_f2w1, 512, 1024);
  tcast_kernel<<<dim3(16, 32), blk, 0, stream>>>(ffn2_w2, w_f2w2, 1024, 512);
  concat3_kernel<<<6, blk, 0, stream>>>(bq, bk, bv, bqkv);
  rope_tbl_kernel<<<128, blk, 0, stream>>>(rtbl);

  // ---- FFN1: y = x + 0.5*(swish(x@w1+b1)@w2+b2)   (residual = xb bf16)
  mgemm<64, 64, 1><<<dim3(16, 128), blk, 0, stream>>>(xb, w_f1w1, ffn1_b1, nullptr, nullptr, h1, M_ROWS, 1024, 512);
  mgemm<64, 64, 3><<<dim3(8, 128), blk, 0, stream>>>(h1, w_f1w2, ffn1_b2, nullptr, xb, buf_y, M_ROWS, 512, 1024);

  // ---- MHSA (table-RoPE fused into QKV epilogue; v staged->coalesced v^T)
  ln_kernel<short><<<M_ROWS, blk, 0, stream>>>(buf_y, ln_att_g, ln_att_b, lnq);
  mgemm<128, 128, 4><<<dim3(12, 64), blk, 0, stream>>>(lnq, w_qkv, bqkv, rtbl, nullptr, qkv16, M_ROWS, 1536, 512);
  attn_mfma_kernel<<<1024, blk, 0, stream>>>(qkv16, qkv16 + 4194304, qkv16 + 8388608, ctx);
  mgemm<64, 64, 2><<<dim3(8, 128), blk, 0, stream>>>(ctx, w_wo, bo, nullptr, buf_y, buf_y, M_ROWS, 512, 512);

  // ---- Conv module (pw1+GLU fused; BN chain in bf16)
  ln_kernel<short><<<M_ROWS, blk, 0, stream>>>(buf_y, cln_g, cln_b, lnc);
  mgemm<128, 128, 6><<<dim3(16, 64), blk, 0, stream>>>(lnc, w_pw1, pw1_b, nullptr, nullptr, gluo, M_ROWS, 2048, 512);
  dwconv_kernel<<<4096, blk, 0, stream>>>(gluo, dw_w, dw_b, dwo16);
  bn_stats_kernel<<<256, blk, 0, stream>>>(dwo16, ps, pq);
  bn_finalize_kernel<<<4, blk, 0, stream>>>(ps, pq, stats);
  bn_apply_kernel<<<8192, blk, 0, stream>>>(dwo16, bn_g, bn_b, stats, bno);
  mgemm<64, 64, 2><<<dim3(8, 128), blk, 0, stream>>>(bno, w_pw2, pw2_b, nullptr, buf_y, buf_y, M_ROWS, 512, 1024);

  // ---- FFN2 (A-input read directly from bf16 residual stream)
  mgemm<64, 64, 1><<<dim3(16, 128), blk, 0, stream>>>(buf_y, w_f2w1, ffn2_b1, nullptr, nullptr, h1, M_ROWS, 1024, 512);
  mgemm<64, 64, 3><<<dim3(8, 128), blk, 0, stream>>>(h1, w_f2w2, ffn2_b2, nullptr, buf_y, buf_y, M_ROWS, 512, 1024);

  // ---- Final LN -> d_out (f32)
  ln_kernel<float><<<M_ROWS, blk, 0, stream>>>(buf_y, ln_out_g, ln_out_b, (float*)d_out);
}

// Round 11
// 331.416 us; speedup vs baseline: 1.0975x; 1.0975x over previous
//
#include <hip/hip_runtime.h>
#include <hip/hip_bf16.h>

// ---------------------------------------------------------------------------
// Conformer block: bf16-MFMA GEMMs (XCD-swizzled, counted-vmcnt pipelined) +
// bf16-MFMA flash attention (async-staged K/V, defer-max, setprio) +
// LDS-tiled depthwise conv. RoPE fused into QKV epilogue (table); GLU fused
// into pw1 (packed weights); bf16 residual stream.
// B=8, T=1024, D=512, HID=1024, C=1024, K=31, H=8, dh=64.  M = B*T = 8192.
// ---------------------------------------------------------------------------

#define M_ROWS 8192

using bf16x8 = __attribute__((ext_vector_type(8))) short;
using f32x4  = __attribute__((ext_vector_type(4))) float;
using s8v    = __attribute__((ext_vector_type(8))) short;
using s4v    = __attribute__((ext_vector_type(4))) short;

__device__ __forceinline__ float sigmoid_(float v) { return 1.f / (1.f + expf(-v)); }

__device__ __forceinline__ float bf2f(short s) {
  return __uint_as_float(((unsigned)(unsigned short)s) << 16);
}
__device__ __forceinline__ short f2bf(float f) {
  unsigned u = __float_as_uint(f);
  unsigned r = (u + 0x7fffu + ((u >> 16) & 1u)) >> 16;
  return (short)r;
}

__device__ __forceinline__ void gl16(const void* g, void* l) {
  __builtin_amdgcn_global_load_lds((const __attribute__((address_space(1))) void*)g,
                                   (__attribute__((address_space(3))) void*)l, 16, 0, 0);
}

// ---------------------------------------------------------------------------
// bf16 MFMA GEMM: outb[M,N] = epi(A[M,K] @ Bt[N,K]^T + bias). BK=32.
// BM=128: 2x2 wave grid. BM=64: 1x4. Counted-vmcnt 2-buffer K-loop.
// EPI: 1 swish->bf16 | 2 resb+acc+bias->bf16 | 3 resb+0.5*(acc+bias)->bf16
//      4 QKV (BM=128): table-RoPE q/k ->bf16 (B,H,T,64); v->bf16 (B,H,64,T)
//      6 pw1+GLU (BM=128, packed weights): a*sigmoid(gate)->bf16
// ---------------------------------------------------------------------------
template <int BM, int BN, int EPI>
__global__ __launch_bounds__(256) void mgemm(
    const short* __restrict__ A, const short* __restrict__ Bt,
    const float* __restrict__ bias, const float* __restrict__ res,
    const short* __restrict__ resb, short* __restrict__ outb, int M, int N, int K) {
  constexpr int WR = BM / 64;        // wave-grid rows
  constexpr int WC = 4 / WR;         // wave-grid cols
  constexpr int NF = BN / (16 * WC); // N-frags per wave
  __shared__ __align__(16) short As[2][BM * 32];
  __shared__ __align__(16) short Bs[2][BN * 32];
  __shared__ __align__(16) short vstg[EPI == 4 ? 64 * 132 : 1];  // v^T staging
  const int tid = threadIdx.x;
  const int lane = tid & 63, wid = tid >> 6;
  const int wr = wid / WC, wc = wid % WC;
  // ---- XCD-aware swizzle: contiguous bm-chunk per XCD for A-panel L2 reuse.
  const int nbx = gridDim.x;
  const int nwg = nbx * gridDim.y;
  int id = blockIdx.y * nbx + blockIdx.x;
  id = (id & 7) * (nwg >> 3) + (id >> 3);
  const int bm = (id / nbx) * BM;
  const int bn = (id % nbx) * BN;
  f32x4 acc[4][NF];
#pragma unroll
  for (int m = 0; m < 4; ++m)
#pragma unroll
    for (int n = 0; n < NF; ++n) acc[m][n] = (f32x4){0.f, 0.f, 0.f, 0.f};
  const short* Ablk = A + (size_t)bm * K;
  const short* Bblk = Bt + (size_t)bn * K;
  const int r0 = tid >> 2, ks = (tid & 3) << 3;  // staging row / k-offset
#define STAGE(buf, k0)                                                              \
  do {                                                                              \
    gl16(Ablk + (size_t)r0 * K + (k0) + ks, (char*)As[buf] + wid * 1024);           \
    if (BM == 128)                                                                  \
      gl16(Ablk + (size_t)(r0 + 64) * K + (k0) + ks, (char*)As[buf] + 4096 + wid * 1024); \
    gl16(Bblk + (size_t)r0 * K + (k0) + ks, (char*)Bs[buf] + wid * 1024);           \
    if (BN == 128)                                                                  \
      gl16(Bblk + (size_t)(r0 + 64) * K + (k0) + ks, (char*)Bs[buf] + 4096 + wid * 1024); \
  } while (0)

  STAGE(0, 0);
  STAGE(1, 32);
  const int NS = K >> 5;
  const int arow = wr * 64 + (lane & 15);
  const int brow = wc * (BN / WC) + (lane & 15);
  const int koff = (lane >> 4) << 3;
  for (int i = 0; i < NS; ++i) {
    // wait: this iter's buffer landed; next iter's stage may remain in flight.
    if (i + 1 < NS) {
      if constexpr (BM + BN == 256) asm volatile("s_waitcnt vmcnt(4)" ::: "memory");
      else if constexpr (BM + BN == 192) asm volatile("s_waitcnt vmcnt(3)" ::: "memory");
      else asm volatile("s_waitcnt vmcnt(2)" ::: "memory");
    } else {
      asm volatile("s_waitcnt vmcnt(0)" ::: "memory");
    }
    __builtin_amdgcn_s_barrier();
    asm volatile("" ::: "memory");  // fence: no LDS read hoists above barrier
    const int cur = i & 1;
    bf16x8 af[4], bfr[NF];
#pragma unroll
    for (int m = 0; m < 4; ++m)
      af[m] = *reinterpret_cast<const bf16x8*>(&As[cur][(arow + m * 16) * 32 + koff]);
#pragma unroll
    for (int n = 0; n < NF; ++n)
      bfr[n] = *reinterpret_cast<const bf16x8*>(&Bs[cur][(brow + n * 16) * 32 + koff]);
    asm volatile("s_waitcnt lgkmcnt(0)" ::: "memory");  // my reads in regs
    __builtin_amdgcn_s_barrier();                       // all waves' reads done
    if (((i + 2) << 5) < K) STAGE(cur, (i + 2) << 5);   // safe to overwrite
#pragma unroll
    for (int m = 0; m < 4; ++m)
#pragma unroll
      for (int n = 0; n < NF; ++n)
        acc[m][n] = __builtin_amdgcn_mfma_f32_16x16x32_bf16(af[m], bfr[n], acc[m][n], 0, 0, 0);
  }
#undef STAGE
  const int orow0 = bm + wr * 64 + ((lane >> 4) << 2);
  const int ocol0 = bn + wc * (BN / WC) + (lane & 15);

  if constexpr (EPI == 4) {
    // ---- QKV epilogue. sel: 0=q (pos=h, *scale), 1=k (pos=t), 2=v^T.
    const int sel = bn >> 9;
    const float2* tbl = (const float2*)res;  // [1024][32] (cos,sin)
    if (sel == 2) {
      const int b_ = bm >> 10, t0v = bm & 1023;
      const int hb = (bn & 511) >> 6;
#pragma unroll
      for (int pass = 0; pass < 2; ++pass) {
        __syncthreads();
        if (wc == pass) {
#pragma unroll
          for (int m = 0; m < 4; ++m) {
            const int rl = wr * 64 + ((lane >> 4) << 2) + m * 16;  // t_local
#pragma unroll
            for (int n = 0; n < NF; ++n) {
              const int dl = (lane & 15) + n * 16;
              const float bv = bias[bn + wc * 64 + dl];
#pragma unroll
              for (int r = 0; r < 4; ++r)
                vstg[dl * 132 + rl + r] = f2bf(acc[m][n][r] + bv);
            }
          }
        }
        __syncthreads();
#pragma unroll
        for (int it = 0; it < 4; ++it) {
          const int c = tid + (it << 8);  // 0..1023
          const int d = c >> 4, t8 = (c & 15) << 3;
          const s8v val = *reinterpret_cast<const s8v*>(&vstg[d * 132 + t8]);
          *reinterpret_cast<s8v*>(
              &outb[(size_t)8388608 + (((size_t)((b_ << 3) + hb + pass)) << 16) +
                    ((size_t)d << 10) + t0v + t8]) = val;
        }
      }
    } else {
      const float qsc = (sel == 0) ? 0.04419417382415922f : 1.f;  // 1/sqrt(512)
#pragma unroll
      for (int n = 0; n < NF; ++n) {
        const int col = ocol0 + n * 16;
        const int h = (col >> 6) & 7, d = col & 63;
        const int p = d >> 1;
        const float bv = bias[col];
#pragma unroll
        for (int m = 0; m < 4; ++m) {
#pragma unroll
          for (int r = 0; r < 4; ++r) {
            const int row = orow0 + m * 16 + r;
            const int b_ = row >> 10, t_ = row & 1023;
            const int pos = (sel == 0) ? h : t_;
            const float2 cs = tbl[pos * 32 + p];
            float vv = acc[m][n][r] + bv;
            const float pv = __shfl_xor(vv, 1);
            float o = ((lane & 1) == 0) ? (vv * cs.x - pv * cs.y) : (vv * cs.x + pv * cs.y);
            outb[(size_t)sel * 4194304 + (((size_t)((b_ << 3) + h)) << 16) + ((size_t)t_ << 6) + d] =
                f2bf(o * qsc);
          }
        }
      }
    }
  } else if constexpr (EPI == 6) {
    // ---- pw1 + GLU: packed weights put (a, gate) in frags (2np, 2np+1).
    const int j = bn >> 7;
#pragma unroll
    for (int m = 0; m < 4; ++m) {
#pragma unroll
      for (int np = 0; np < NF / 2; ++np) {
        const int gc = (j << 6) + ((wc * 2 + np) << 4) + (lane & 15);
        const float ba = bias[gc];
        const float bg = bias[1024 + gc];
#pragma unroll
        for (int r = 0; r < 4; ++r) {
          const int row = orow0 + m * 16 + r;
          const float a = acc[m][2 * np][r] + ba;
          const float g = acc[m][2 * np + 1][r] + bg;
          outb[(size_t)row * 1024 + gc] = f2bf(a * sigmoid_(g));
        }
      }
    }
  } else {
#pragma unroll
    for (int m = 0; m < 4; ++m) {
#pragma unroll
      for (int n = 0; n < NF; ++n) {
        const int col = ocol0 + n * 16;
        const float bv = bias[col];
#pragma unroll
        for (int r = 0; r < 4; ++r) {
          const int row = orow0 + m * 16 + r;
          float v = acc[m][n][r] + bv;
          if constexpr (EPI == 1) {
            v = v * sigmoid_(v);
          } else if constexpr (EPI == 2) {
            v += bf2f(resb[(size_t)row * N + col]);
          } else if constexpr (EPI == 3) {
            v = bf2f(resb[(size_t)row * N + col]) + 0.5f * v;
          }
          outb[(size_t)row * N + col] = f2bf(v);
        }
      }
    }
  }
}

// ---------------------------------------------------------------------------
// RoPE table: tbl[t][p] = (cos, sin) of t * 10000^(-p/32). 1024x32 float2.
// ---------------------------------------------------------------------------
__global__ __launch_bounds__(256) void rope_tbl_kernel(float* __restrict__ tbl) {
  const int i = blockIdx.x * 256 + threadIdx.x;  // 32768
  const int t = i >> 5, p = i & 31;
  const float inv = exp2f(-(float)p * 0.41524101186092f);  // 10000^(-p/32)
  float s, c;
  sincosf((float)t * inv, &s, &c);
  tbl[i * 2] = c;
  tbl[i * 2 + 1] = s;
}

// ---------------------------------------------------------------------------
// LayerNorm over last dim (512), bf16 input. One block (256 threads) per row.
// ---------------------------------------------------------------------------
template <typename OT>
__global__ __launch_bounds__(256) void ln_kernel(
    const short* __restrict__ in, const float* __restrict__ g,
    const float* __restrict__ b, OT* __restrict__ out) {
  __shared__ float sm[4];
  const size_t row = blockIdx.x;
  const int tid = threadIdx.x;
  const short* x = in + (row << 9);
  const int pr = *reinterpret_cast<const int*>(&x[tid << 1]);
  const float v0 = bf2f((short)(pr & 0xffff));
  const float v1 = bf2f((short)(((unsigned)pr) >> 16));
  float s = v0 + v1;
  for (int o = 32; o; o >>= 1) s += __shfl_xor(s, o);
  if ((tid & 63) == 0) sm[tid >> 6] = s;
  __syncthreads();
  const float mean = (sm[0] + sm[1] + sm[2] + sm[3]) * (1.f / 512.f);
  __syncthreads();
  const float d0 = v0 - mean, d1 = v1 - mean;
  float q = d0 * d0 + d1 * d1;
  for (int o = 32; o; o >>= 1) q += __shfl_xor(q, o);
  if ((tid & 63) == 0) sm[tid >> 6] = q;
  __syncthreads();
  const float var = (sm[0] + sm[1] + sm[2] + sm[3]) * (1.f / 512.f);
  const float inv = rsqrtf(var + 1e-5f);
  const float2 gv = *reinterpret_cast<const float2*>(&g[tid << 1]);
  const float2 bv = *reinterpret_cast<const float2*>(&b[tid << 1]);
  const float o0 = d0 * inv * gv.x + bv.x;
  const float o1 = d1 * inv * gv.y + bv.y;
  if constexpr (sizeof(OT) == 2) {
    const int pk = (int)(unsigned short)f2bf(o0) | ((int)(unsigned short)f2bf(o1) << 16);
    *reinterpret_cast<int*>(&out[(row << 9) + (tid << 1)]) = pk;
  } else {
    float2 o = {o0, o1};
    *reinterpret_cast<float2*>(&out[(row << 9) + (tid << 1)]) = o;
  }
}

// ---------------------------------------------------------------------------
// MFMA flash attention. One block (4 waves) per (b,h,64-q-tile), XCD-swizzled.
// q,k bf16 (B,H,T,64) pre-roped (q pre-scaled); v bf16 TRANSPOSED (B,H,64,T).
// Async-staged K/V (T14), defer-max softmax (T13, THR=8), setprio (T5).
// ---------------------------------------------------------------------------
__global__ __launch_bounds__(256) void attn_mfma_kernel(
    const short* __restrict__ q, const short* __restrict__ k,
    const short* __restrict__ vt, short* __restrict__ ctx) {
  __shared__ __align__(16) short Qs[64][72];   // [q][d]
  __shared__ __align__(16) short Ks[64][72];   // [k][d]
  __shared__ __align__(16) short VsT[64][72];  // [d][k]
  __shared__ __align__(16) short Ps[64][72];   // [q][k]
  const int bx = ((blockIdx.x & 7) << 7) | (blockIdx.x >> 3);  // nwg=1024, cpx=128
  const int bh = bx >> 4, qt = bx & 15;
  const int b_ = bh >> 3, h_ = bh & 7;
  const int tid = threadIdx.x, lane = tid & 63, w = tid >> 6;
  const int t0 = qt << 6;
  const short* qbase = q + ((size_t)bh << 16) + ((size_t)t0 << 6);
  const short* kbase = k + ((size_t)bh << 16);
  const short* vtbase = vt + ((size_t)bh << 16);
  const int sr = tid >> 2, scg = (tid & 3) << 4;
  // ---- stage Q and tile 0 of K/V
  {
    const s8v a = *reinterpret_cast<const s8v*>(&qbase[(size_t)sr * 64 + scg]);
    const s8v b = *reinterpret_cast<const s8v*>(&qbase[(size_t)sr * 64 + scg + 8]);
    *reinterpret_cast<s8v*>(&Qs[sr][scg]) = a;
    *reinterpret_cast<s8v*>(&Qs[sr][scg + 8]) = b;
    const s8v k0a = *reinterpret_cast<const s8v*>(&kbase[(size_t)sr * 64 + scg]);
    const s8v k0b = *reinterpret_cast<const s8v*>(&kbase[(size_t)sr * 64 + scg + 8]);
    *reinterpret_cast<s8v*>(&Ks[sr][scg]) = k0a;
    *reinterpret_cast<s8v*>(&Ks[sr][scg + 8]) = k0b;
    const s8v v0a = *reinterpret_cast<const s8v*>(&vtbase[((size_t)sr << 10) + scg]);
    const s8v v0b = *reinterpret_cast<const s8v*>(&vtbase[((size_t)sr << 10) + scg + 8]);
    *reinterpret_cast<s8v*>(&VsT[sr][scg]) = v0a;
    *reinterpret_cast<s8v*>(&VsT[sr][scg + 8]) = v0b;
  }
  __syncthreads();
  const int fr = lane & 15, fg = lane >> 4;
  const int koff0 = fg << 3;
  bf16x8 qf[2];
  qf[0] = *reinterpret_cast<const bf16x8*>(&Qs[w * 16 + fr][koff0]);
  qf[1] = *reinterpret_cast<const bf16x8*>(&Qs[w * 16 + fr][32 + koff0]);
  float m[4] = {-1e30f, -1e30f, -1e30f, -1e30f};
  float l[4] = {0.f, 0.f, 0.f, 0.f};
  f32x4 outv[4];
#pragma unroll
  for (int n = 0; n < 4; ++n) outv[n] = (f32x4){0.f, 0.f, 0.f, 0.f};

  for (int i = 0; i < 16; ++i) {
    // ---- T14: issue next tile's global loads; consumed after the PV barrier.
    s8v nk0, nk1, nv0, nv1;
    const bool pf = (i < 15);
    if (pf) {
      const int kn = (i + 1) << 6;
      nk0 = *reinterpret_cast<const s8v*>(&kbase[(size_t)(kn + sr) * 64 + scg]);
      nk1 = *reinterpret_cast<const s8v*>(&kbase[(size_t)(kn + sr) * 64 + scg + 8]);
      nv0 = *reinterpret_cast<const s8v*>(&vtbase[((size_t)sr << 10) + kn + scg]);
      nv1 = *reinterpret_cast<const s8v*>(&vtbase[((size_t)sr << 10) + kn + scg + 8]);
    }
    // ---- S = Q @ K^T
    f32x4 sacc[4];
    __builtin_amdgcn_s_setprio(1);
#pragma unroll
    for (int n = 0; n < 4; ++n) {
      sacc[n] = (f32x4){0.f, 0.f, 0.f, 0.f};
      const bf16x8 kf0 = *reinterpret_cast<const bf16x8*>(&Ks[n * 16 + fr][koff0]);
      const bf16x8 kf1 = *reinterpret_cast<const bf16x8*>(&Ks[n * 16 + fr][32 + koff0]);
      sacc[n] = __builtin_amdgcn_mfma_f32_16x16x32_bf16(qf[0], kf0, sacc[n], 0, 0, 0);
      sacc[n] = __builtin_amdgcn_mfma_f32_16x16x32_bf16(qf[1], kf1, sacc[n], 0, 0, 0);
    }
    __builtin_amdgcn_s_setprio(0);
    // ---- online softmax with defer-max (THR=8)
    float vm[4];
#pragma unroll
    for (int r = 0; r < 4; ++r)
      vm[r] = fmaxf(fmaxf(sacc[0][r], sacc[1][r]), fmaxf(sacc[2][r], sacc[3][r]));
    const bool ok = vm[0] <= m[0] + 8.f && vm[1] <= m[1] + 8.f &&
                    vm[2] <= m[2] + 8.f && vm[3] <= m[3] + 8.f;
    if (__all(ok)) {
      // fast path: keep old max, no rescale (P bounded by e^8)
#pragma unroll
      for (int r = 0; r < 4; ++r) {
        const float p0 = __expf(sacc[0][r] - m[r]), p1 = __expf(sacc[1][r] - m[r]);
        const float p2 = __expf(sacc[2][r] - m[r]), p3 = __expf(sacc[3][r] - m[r]);
        l[r] += p0 + p1 + p2 + p3;
        const int qr = w * 16 + (fg << 2) + r;
        Ps[qr][fr] = f2bf(p0);
        Ps[qr][16 + fr] = f2bf(p1);
        Ps[qr][32 + fr] = f2bf(p2);
        Ps[qr][48 + fr] = f2bf(p3);
      }
    } else {
#pragma unroll
      for (int r = 0; r < 4; ++r) {
        float rm = vm[r];
        rm = fmaxf(rm, __shfl_xor(rm, 1));
        rm = fmaxf(rm, __shfl_xor(rm, 2));
        rm = fmaxf(rm, __shfl_xor(rm, 4));
        rm = fmaxf(rm, __shfl_xor(rm, 8));
        const float nm = fmaxf(m[r], rm);
        const float al = __expf(m[r] - nm);
        m[r] = nm;
        const float p0 = __expf(sacc[0][r] - nm), p1 = __expf(sacc[1][r] - nm);
        const float p2 = __expf(sacc[2][r] - nm), p3 = __expf(sacc[3][r] - nm);
        l[r] = l[r] * al + (p0 + p1 + p2 + p3);
        outv[0][r] *= al; outv[1][r] *= al; outv[2][r] *= al; outv[3][r] *= al;
        const int qr = w * 16 + (fg << 2) + r;
        Ps[qr][fr] = f2bf(p0);
        Ps[qr][16 + fr] = f2bf(p1);
        Ps[qr][32 + fr] = f2bf(p2);
        Ps[qr][48 + fr] = f2bf(p3);
      }
    }
    __syncthreads();  // Ps visible; all QK reads of Ks done
    // ---- out += P @ V
    const bf16x8 pa0 = *reinterpret_cast<const bf16x8*>(&Ps[w * 16 + fr][koff0]);
    const bf16x8 pa1 = *reinterpret_cast<const bf16x8*>(&Ps[w * 16 + fr][32 + koff0]);
    __builtin_amdgcn_s_setprio(1);
#pragma unroll
    for (int n = 0; n < 4; ++n) {
      const bf16x8 vf0 = *reinterpret_cast<const bf16x8*>(&VsT[n * 16 + fr][koff0]);
      const bf16x8 vf1 = *reinterpret_cast<const bf16x8*>(&VsT[n * 16 + fr][32 + koff0]);
      outv[n] = __builtin_amdgcn_mfma_f32_16x16x32_bf16(pa0, vf0, outv[n], 0, 0, 0);
      outv[n] = __builtin_amdgcn_mfma_f32_16x16x32_bf16(pa1, vf1, outv[n], 0, 0, 0);
    }
    __builtin_amdgcn_s_setprio(0);
    __syncthreads();  // all PV reads of VsT/Ps done
    if (pf) {
      *reinterpret_cast<s8v*>(&Ks[sr][scg]) = nk0;
      *reinterpret_cast<s8v*>(&Ks[sr][scg + 8]) = nk1;
      *reinterpret_cast<s8v*>(&VsT[sr][scg]) = nv0;
      *reinterpret_cast<s8v*>(&VsT[sr][scg + 8]) = nv1;
      __syncthreads();
    }
  }
#pragma unroll
  for (int r = 0; r < 4; ++r) {
    float L = l[r];
    L += __shfl_xor(L, 1);
    L += __shfl_xor(L, 2);
    L += __shfl_xor(L, 4);
    L += __shfl_xor(L, 8);
    const float inv = 1.f / L;
    const int t = t0 + w * 16 + (fg << 2) + r;
    const size_t base = (((size_t)((b_ << 10) | t)) << 9) + (h_ << 6);
#pragma unroll
    for (int n = 0; n < 4; ++n)
      ctx[base + n * 16 + fr] = f2bf(outv[n][r] * inv);
  }
}

// ---------------------------------------------------------------------------
// f32 -> bf16 cast (8 elems/thread).
// ---------------------------------------------------------------------------
__global__ __launch_bounds__(256) void cast_bf16_kernel(const float* __restrict__ in,
                                                        short* __restrict__ out) {
  const size_t i = (size_t)blockIdx.x * 256 + threadIdx.x;
  const float4 a = *reinterpret_cast<const float4*>(&in[i * 8]);
  const float4 b = *reinterpret_cast<const float4*>(&in[i * 8 + 4]);
  s8v o = { f2bf(a.x), f2bf(a.y), f2bf(a.z), f2bf(a.w),
            f2bf(b.x), f2bf(b.y), f2bf(b.z), f2bf(b.w) };
  *reinterpret_cast<s8v*>(&out[i * 8]) = o;
}

// ---------------------------------------------------------------------------
// pw1 weight pack: [2048][512] f32 -> interleaved [2048][512] bf16.
// ---------------------------------------------------------------------------
__global__ __launch_bounds__(256) void pack_pw1_kernel(const float* __restrict__ w,
                                                       short* __restrict__ out) {
  const int idx = blockIdx.x * 256 + threadIdx.x;  // 2048*64
  const int pc = idx >> 6, kk = (idx & 63) << 3;
  const int j = pc >> 7, s = (pc >> 4) & 7, fr = pc & 15;
  const int oc = ((s & 1) << 10) + (j << 6) + ((s >> 1) << 4) + fr;
  const float4 a = *reinterpret_cast<const float4*>(&w[(size_t)oc * 512 + kk]);
  const float4 b = *reinterpret_cast<const float4*>(&w[(size_t)oc * 512 + kk + 4]);
  s8v o = { f2bf(a.x), f2bf(a.y), f2bf(a.z), f2bf(a.w),
            f2bf(b.x), f2bf(b.y), f2bf(b.z), f2bf(b.w) };
  *reinterpret_cast<s8v*>(&out[(size_t)pc * 512 + kk]) = o;
}

// ---------------------------------------------------------------------------
// Transpose-cast: in [K,N] f32 -> out [N,K] bf16. Grid (N/32, K/32).
// ---------------------------------------------------------------------------
__global__ __launch_bounds__(256) void tcast_kernel(const float* __restrict__ in,
                                                    short* __restrict__ out, int K, int N) {
  __shared__ float t[32][33];
  const int n0 = blockIdx.x << 5, k0 = blockIdx.y << 5;
  const int tx = threadIdx.x & 31, ty = threadIdx.x >> 5;
  for (int r = ty; r < 32; r += 8) t[r][tx] = in[(size_t)(k0 + r) * N + n0 + tx];
  __syncthreads();
  for (int r = ty; r < 32; r += 8) out[(size_t)(n0 + r) * K + k0 + tx] = f2bf(t[tx][r]);
}

__global__ __launch_bounds__(256) void concat3_kernel(const float* a, const float* b,
                                                      const float* c, float* o) {
  const int i = blockIdx.x * 256 + threadIdx.x;  // 1536
  o[i] = i < 512 ? a[i] : (i < 1024 ? b[i - 512] : c[i - 1024]);
}

// ---------------------------------------------------------------------------
// LDS-tiled depthwise conv K=31 SAME. in bf16 (8,1024,1024), out bf16.
// Block = (b, 256-t tile, 64-ch tile) -> 512 blocks. Input tile (286 x 64)
// staged once in LDS (halo 1.12x); weights (31 x 64) in LDS; thread computes
// 8 t x 8 ch with kk-outer loops (weight reads broadcast).
// ---------------------------------------------------------------------------
__global__ __launch_bounds__(256) void dwconv_kernel(
    const short* __restrict__ in, const float* __restrict__ w,
    const float* __restrict__ bias, short* __restrict__ out) {
  __shared__ __align__(16) short tile[286 * 72];  // [t][ch], stride 72 (144B, 16B-mult)
  __shared__ float wlds[31 * 64];                 // [kk][ch]
  const int id = blockIdx.x;  // 512
  const int ct = id & 15, tt = (id >> 4) & 3;
  const size_t b = id >> 6;
  const int c0 = ct << 6, t0 = tt << 8;
  const int tid = threadIdx.x;
  // ---- stage weights
  for (int i = tid; i < 31 * 64; i += 256) {
    const int kk = i >> 6, c = i & 63;
    wlds[i] = w[kk * 1024 + c0 + c];
  }
  // ---- stage input rows t0-15 .. t0+270 (286 rows x 64 ch), zero-padded
  for (int i = tid; i < 286 * 8; i += 256) {
    const int row = i >> 3, seg = i & 7;  // seg = 8 shorts (16B)
    const int gt = t0 - 15 + row;
    s8v val = {};
    if (gt >= 0 && gt < 1024)
      val = *reinterpret_cast<const s8v*>(&in[(b << 20) + ((size_t)gt << 10) + c0 + (seg << 3)]);
    *reinterpret_cast<s8v*>(&tile[row * 72 + (seg << 3)]) = val;
  }
  __syncthreads();
  const int cg = tid & 7, tg = tid >> 3;  // ch-group 0..7, t-group 0..31
  const int tl = tg << 3;                 // local t base
  float acc[8][8];
  const float4 b0 = *reinterpret_cast<const float4*>(&bias[c0 + (cg << 3)]);
  const float4 b1 = *reinterpret_cast<const float4*>(&bias[c0 + (cg << 3) + 4]);
#pragma unroll
  for (int t = 0; t < 8; ++t) {
    acc[t][0] = b0.x; acc[t][1] = b0.y; acc[t][2] = b0.z; acc[t][3] = b0.w;
    acc[t][4] = b1.x; acc[t][5] = b1.y; acc[t][6] = b1.z; acc[t][7] = b1.w;
  }
  for (int kk = 0; kk < 31; ++kk) {
    const float4 w0 = *reinterpret_cast<const float4*>(&wlds[kk * 64 + (cg << 3)]);
    const float4 w1 = *reinterpret_cast<const float4*>(&wlds[kk * 64 + (cg << 3) + 4]);
#pragma unroll
    for (int t = 0; t < 8; ++t) {
      const s8v xv = *reinterpret_cast<const s8v*>(&tile[(tl + t + kk) * 72 + (cg << 3)]);
      acc[t][0] = fmaf(bf2f(xv[0]), w0.x, acc[t][0]);
      acc[t][1] = fmaf(bf2f(xv[1]), w0.y, acc[t][1]);
      acc[t][2] = fmaf(bf2f(xv[2]), w0.z, acc[t][2]);
      acc[t][3] = fmaf(bf2f(xv[3]), w0.w, acc[t][3]);
      acc[t][4] = fmaf(bf2f(xv[4]), w1.x, acc[t][4]);
      acc[t][5] = fmaf(bf2f(xv[5]), w1.y, acc[t][5]);
      acc[t][6] = fmaf(bf2f(xv[6]), w1.z, acc[t][6]);
      acc[t][7] = fmaf(bf2f(xv[7]), w1.w, acc[t][7]);
    }
  }
#pragma unroll
  for (int t = 0; t < 8; ++t) {
    s8v o;
#pragma unroll
    for (int j = 0; j < 8; ++j) o[j] = f2bf(acc[t][j]);
    *reinterpret_cast<s8v*>(&out[(b << 20) + ((size_t)(t0 + tl + t) << 10) + c0 + (cg << 3)]) = o;
  }
}

// ---------------------------------------------------------------------------
// BatchNorm over (B,T) on bf16 y: two-stage deterministic reduction; apply+swish.
// ---------------------------------------------------------------------------
__global__ __launch_bounds__(256) void bn_stats_kernel(
    const short* __restrict__ y, float* __restrict__ ps, float* __restrict__ pq) {
  const int tid = threadIdx.x;
  const int c4 = tid << 2;
  const size_t r0 = (size_t)blockIdx.x * 32;
  float s[4] = {0, 0, 0, 0}, q[4] = {0, 0, 0, 0};
  for (int r = 0; r < 32; ++r) {
    const s4v v = *reinterpret_cast<const s4v*>(&y[((r0 + r) << 10) + c4]);
#pragma unroll
    for (int j = 0; j < 4; ++j) {
      const float f = bf2f(v[j]);
      s[j] += f;
      q[j] = fmaf(f, f, q[j]);
    }
  }
#pragma unroll
  for (int j = 0; j < 4; ++j) {
    ps[(size_t)blockIdx.x * 1024 + c4 + j] = s[j];
    pq[(size_t)blockIdx.x * 1024 + c4 + j] = q[j];
  }
}

__global__ __launch_bounds__(256) void bn_finalize_kernel(
    const float* __restrict__ ps, const float* __restrict__ pq, float* __restrict__ stats) {
  const int c = blockIdx.x * 256 + threadIdx.x;  // 0..1023
  float s = 0.f, q = 0.f;
  for (int i = 0; i < 256; ++i) {
    s += ps[i * 1024 + c];
    q += pq[i * 1024 + c];
  }
  const float mean = s * (1.f / 8192.f);
  const float var = q * (1.f / 8192.f) - mean * mean;
  stats[c] = mean;
  stats[1024 + c] = rsqrtf(fmaxf(var, 0.f) + 1e-5f);
}

__global__ __launch_bounds__(256) void bn_apply_kernel(
    const short* __restrict__ y, const float* __restrict__ g, const float* __restrict__ b,
    const float* __restrict__ stats, short* __restrict__ out) {
  const size_t i = (size_t)blockIdx.x * 256 + threadIdx.x;  // 2M, 4 elems each
  const size_t f = i << 2;
  const int c = (int)(f & 1023);
  const s4v yv = *reinterpret_cast<const s4v*>(&y[f]);
  s4v o;
#pragma unroll
  for (int j = 0; j < 4; ++j) {
    const float v = (bf2f(yv[j]) - stats[c + j]) * stats[1024 + c + j] * g[c + j] + b[c + j];
    o[j] = f2bf(v * sigmoid_(v));
  }
  *reinterpret_cast<s4v*>(&out[f]) = o;
}

// ---------------------------------------------------------------------------
extern "C" void kernel_launch(void* const* d_in, const int* in_sizes, int n_in,
                              void* d_out, int out_size, void* d_ws, size_t ws_size,
                              hipStream_t stream) {
  const float* x        = (const float*)d_in[0];
  const float* ffn1_w1  = (const float*)d_in[1];
  const float* ffn1_b1  = (const float*)d_in[2];
  const float* ffn1_w2  = (const float*)d_in[3];
  const float* ffn1_b2  = (const float*)d_in[4];
  const float* ln_att_g = (const float*)d_in[5];
  const float* ln_att_b = (const float*)d_in[6];
  const float* wq       = (const float*)d_in[7];
  const float* bq       = (const float*)d_in[8];
  const float* wk       = (const float*)d_in[9];
  const float* bk       = (const float*)d_in[10];
  const float* wv       = (const float*)d_in[11];
  const float* bv       = (const float*)d_in[12];
  const float* wo_      = (const float*)d_in[13];
  const float* bo       = (const float*)d_in[14];
  const float* cln_g    = (const float*)d_in[15];
  const float* cln_b    = (const float*)d_in[16];
  const float* pw1_w    = (const float*)d_in[17];
  const float* pw1_b    = (const float*)d_in[18];
  const float* dw_w     = (const float*)d_in[19];
  const float* dw_b     = (const float*)d_in[20];
  const float* bn_g     = (const float*)d_in[21];
  const float* bn_b     = (const float*)d_in[22];
  const float* pw2_w    = (const float*)d_in[23];
  const float* pw2_b    = (const float*)d_in[24];
  const float* ffn2_w1  = (const float*)d_in[25];
  const float* ffn2_b1  = (const float*)d_in[26];
  const float* ffn2_w2  = (const float*)d_in[27];
  const float* ffn2_b2  = (const float*)d_in[28];
  const float* ln_out_g = (const float*)d_in[29];
  const float* ln_out_b = (const float*)d_in[30];

  char* wsb = (char*)d_ws;
  const size_t MB = 1u << 20;
  // Region A: residual stream bf16 (8 MB)
  short* buf_y = (short*)(wsb);
  // Region B (64 MB, phase-overlaid)
  char* Bre = wsb + 16 * MB;
  short* qkv16 = (short*)(Bre);            // MHSA: q,k (B,H,T,64) + v^T (B,H,64,T), 24 MB
  short* lnq  = (short*)(Bre + 48 * MB);   //        LN out bf16 (8 MB)
  short* ctx  = (short*)(Bre + 56 * MB);   //        ctx bf16 (8 MB)
  short* h1   = (short*)(Bre);             // FFN: hidden bf16 (16 MB)
  short* xb   = (short*)(Bre + 16 * MB);   // x bf16 (8 MB): FFN1 A-input + residual
  short* gluo = (short*)(Bre);             // conv: fused pw1+GLU out bf16 (16 MB)
  short* bno  = (short*)(Bre + 48 * MB);   //       bn out bf16 (16 MB)
  // Region C (32 MB, phase-overlaid)
  char* Cre = wsb + 80 * MB;
  short* lnc  = (short*)(Cre);             // conv LN out bf16 (8 MB)
  short* dwo16= (short*)(Cre + 8 * MB);    // dwconv out bf16 (16 MB)
  // Region D: weights / stats / rope table (~13 MB)
  char* Dre = wsb + 112 * MB;
  short* w_f1w1 = (short*)(Dre);            // [1024,512]
  short* w_f1w2 = (short*)(Dre + 1 * MB);   // [512,1024]
  short* w_qkv  = (short*)(Dre + 2 * MB);   // [1536,512]
  short* w_wo   = (short*)(Dre + 3 * MB + 512 * 1024);  // [512,512]
  short* w_pw1  = (short*)(Dre + 4 * MB);   // [2048,512] packed-interleaved
  short* w_pw2  = (short*)(Dre + 6 * MB);   // [512,1024]
  short* w_f2w1 = (short*)(Dre + 7 * MB);   // [1024,512]
  short* w_f2w2 = (short*)(Dre + 8 * MB);   // [512,1024]
  float* bqkv   = (float*)(Dre + 9 * MB);   // [1536]
  float* ps     = (float*)(Dre + 9 * MB + 8192);
  float* pq     = (float*)(Dre + 10 * MB + 8192);
  float* stats  = (float*)(Dre + 11 * MB + 8192);
  float* rtbl   = (float*)(Dre + 12 * MB);  // [1024][32] float2 = 256 KB

  const dim3 blk(256);

  // ---- input/weight prep (bf16 casts / transposes / packs), graph-safe
  cast_bf16_kernel<<<2048, blk, 0, stream>>>(x, xb);
  tcast_kernel<<<dim3(32, 16), blk, 0, stream>>>(ffn1_w1, w_f1w1, 512, 1024);
  tcast_kernel<<<dim3(16, 32), blk, 0, stream>>>(ffn1_w2, w_f1w2, 1024, 512);
  tcast_kernel<<<dim3(16, 16), blk, 0, stream>>>(wq, w_qkv, 512, 512);
  tcast_kernel<<<dim3(16, 16), blk, 0, stream>>>(wk, w_qkv + 512 * 512, 512, 512);
  tcast_kernel<<<dim3(16, 16), blk, 0, stream>>>(wv, w_qkv + 1024 * 512, 512, 512);
  tcast_kernel<<<dim3(16, 16), blk, 0, stream>>>(wo_, w_wo, 512, 512);
  pack_pw1_kernel<<<512, blk, 0, stream>>>(pw1_w, w_pw1);
  cast_bf16_kernel<<<256, blk, 0, stream>>>(pw2_w, w_pw2);
  tcast_kernel<<<dim3(32, 16), blk, 0, stream>>>(ffn2_w1, w_f2w1, 512, 1024);
  tcast_kernel<<<dim3(16, 32), blk, 0, stream>>>(ffn2_w2, w_f2w2, 1024, 512);
  concat3_kernel<<<6, blk, 0, stream>>>(bq, bk, bv, bqkv);
  rope_tbl_kernel<<<128, blk, 0, stream>>>(rtbl);

  // ---- FFN1: y = x + 0.5*(swish(x@w1+b1)@w2+b2)   (residual = xb bf16)
  mgemm<64, 64, 1><<<dim3(16, 128), blk, 0, stream>>>(xb, w_f1w1, ffn1_b1, nullptr, nullptr, h1, M_ROWS, 1024, 512);
  mgemm<64, 64, 3><<<dim3(8, 128), blk, 0, stream>>>(h1, w_f1w2, ffn1_b2, nullptr, xb, buf_y, M_ROWS, 512, 1024);

  // ---- MHSA (table-RoPE fused into QKV epilogue; v staged->coalesced v^T)
  ln_kernel<short><<<M_ROWS, blk, 0, stream>>>(buf_y, ln_att_g, ln_att_b, lnq);
  mgemm<128, 128, 4><<<dim3(12, 64), blk, 0, stream>>>(lnq, w_qkv, bqkv, rtbl, nullptr, qkv16, M_ROWS, 1536, 512);
  attn_mfma_kernel<<<1024, blk, 0, stream>>>(qkv16, qkv16 + 4194304, qkv16 + 8388608, ctx);
  mgemm<64, 64, 2><<<dim3(8, 128), blk, 0, stream>>>(ctx, w_wo, bo, nullptr, buf_y, buf_y, M_ROWS, 512, 512);

  // ---- Conv module (pw1+GLU fused; LDS-tiled dwconv; BN chain in bf16)
  ln_kernel<short><<<M_ROWS, blk, 0, stream>>>(buf_y, cln_g, cln_b, lnc);
  mgemm<128, 128, 6><<<dim3(16, 64), blk, 0, stream>>>(lnc, w_pw1, pw1_b, nullptr, nullptr, gluo, M_ROWS, 2048, 512);
  dwconv_kernel<<<512, blk, 0, stream>>>(gluo, dw_w, dw_b, dwo16);
  bn_stats_kernel<<<256, blk, 0, stream>>>(dwo16, ps, pq);
  bn_finalize_kernel<<<4, blk, 0, stream>>>(ps, pq, stats);
  bn_apply_kernel<<<8192, blk, 0, stream>>>(dwo16, bn_g, bn_b, stats, bno);
  mgemm<64, 64, 2><<<dim3(8, 128), blk, 0, stream>>>(bno, w_pw2, pw2_b, nullptr, buf_y, buf_y, M_ROWS, 512, 1024);

  // ---- FFN2 (A-input read directly from bf16 residual stream)
  mgemm<64, 64, 1><<<dim3(16, 128), blk, 0, stream>>>(buf_y, w_f2w1, ffn2_b1, nullptr, nullptr, h1, M_ROWS, 1024, 512);
  mgemm<64, 64, 3><<<dim3(8, 128), blk, 0, stream>>>(h1, w_f2w2, ffn2_b2, nullptr, buf_y, buf_y, M_ROWS, 512, 1024);

  // ---- Final LN -> d_out (f32)
  ln_kernel<float><<<M_ROWS, blk, 0, stream>>>(buf_y, ln_out_g, ln_out_b, (float*)d_out);
}